// Round 2
// baseline (1241.813 us; speedup 1.0000x reference)
//
#include <hip/hip_runtime.h>
#include <hip/hip_bf16.h>

typedef __attribute__((ext_vector_type(8))) short short8_t;  // 8 bf16 = 4 VGPRs (MFMA A/B frag)
typedef __attribute__((ext_vector_type(4))) float f32x4;     // MFMA C/D frag
using bf16 = __hip_bfloat16;

__device__ __forceinline__ void gload_lds16(const void* g, void* l) {
  __builtin_amdgcn_global_load_lds(
      (const __attribute__((address_space(1))) void*)g,
      (__attribute__((address_space(3))) void*)l, 16, 0, 0);
}

// ---------------------------------------------------------------------------
// fp32 -> bf16 elementwise convert, 8 elems/thread, vectorized
// ---------------------------------------------------------------------------
__global__ __launch_bounds__(256) void cvt_f32_bf16_k(const float* __restrict__ in,
                                                      bf16* __restrict__ out, int n8) {
  int i = blockIdx.x * 256 + threadIdx.x;
  if (i >= n8) return;
  const float4* p4 = (const float4*)in;
  float4 a = p4[2 * i];
  float4 b = p4[2 * i + 1];
  bf16 t[8] = {__float2bfloat16(a.x), __float2bfloat16(a.y),
               __float2bfloat16(a.z), __float2bfloat16(a.w),
               __float2bfloat16(b.x), __float2bfloat16(b.y),
               __float2bfloat16(b.z), __float2bfloat16(b.w)};
  ((short8_t*)out)[i] = *(const short8_t*)t;
}

// ---------------------------------------------------------------------------
// Templated bf16 MFMA GEMM: C[m][n] = alpha * (sum_k A[m][k]*B[n][k] + bias[n])
// 128x128 tile, BK=32, 256 threads = 4 waves (2x2), 16x16x32 MFMA, 4x4 frags/wave.
// OUT_MODE: 0 = bf16 store, 1 = f32 store, 2 = f32 atomicAdd (split-K)
// A_F32:    A is fp32 in global, reg-staged + converted to bf16 on the fly
// TST:      A and B are stored [k][m]/[k][n] (reduction along rows) -> transpose-stage
// Batched via grid.z: off = (batch/HH)*s1 + (batch%HH)*s2 (element units)
// All shapes here are multiples of the tile sizes -> no bounds checks.
// ---------------------------------------------------------------------------
struct GemmP {
  const void* A; const void* B; const float* bias; void* C;
  long lda, ldb, ldc;
  long sA1, sA2, sB1, sB2, sC1, sC2;
  int M, N, K, HH, splitk;
  float alpha;
};

template <int OUT_MODE, int A_F32, int TST>
__global__ __launch_bounds__(256) void gemm_k(GemmP p) {
  __shared__ short As[128 * 32];  // [row m][k], 8 KB
  __shared__ short Bs[128 * 32];  // [row n][k], 8 KB

  const int tid = threadIdx.x;
  const int zz = blockIdx.z;
  const int batch = zz / p.splitk;
  const int slice = zz - batch * p.splitk;
  const int kper = p.K / p.splitk;
  const int k0 = slice * kper;

  const long offA = (long)(batch / p.HH) * p.sA1 + (long)(batch % p.HH) * p.sA2;
  const long offB = (long)(batch / p.HH) * p.sB1 + (long)(batch % p.HH) * p.sB2;
  const long offC = (long)(batch / p.HH) * p.sC1 + (long)(batch % p.HH) * p.sC2;
  const long tile_m = (long)blockIdx.x * 128;
  const long tile_n = (long)blockIdx.y * 128;

  const int lane = tid & 63;
  const int wave = tid >> 6;
  const int wr = wave >> 1;      // wave row (0..1), wave tile 64x64
  const int wc = wave & 1;       // wave col
  const int l16 = lane & 15;
  const int kg = lane >> 4;      // k-group 0..3

  f32x4 acc[4][4];
#pragma unroll
  for (int m = 0; m < 4; ++m)
#pragma unroll
    for (int n = 0; n < 4; ++n) acc[m][n] = (f32x4){0.f, 0.f, 0.f, 0.f};

  const int row_s = tid >> 2;        // staging: 4 threads/row, 64 rows/issue
  const int kc_s = (tid & 3) * 8;    // 8 bf16 (16B) per thread

  for (int kt = k0; kt < k0 + kper; kt += 32) {
    // ---- stage A tile [128][32] ----
    if (A_F32) {
      const float* Ag = (const float*)p.A + offA;
#pragma unroll
      for (int h = 0; h < 2; ++h) {
        const float* src = Ag + (tile_m + h * 64 + row_s) * p.lda + kt + kc_s;
        float4 v0 = *(const float4*)src;
        float4 v1 = *(const float4*)(src + 4);
        bf16 t[8] = {__float2bfloat16(v0.x), __float2bfloat16(v0.y),
                     __float2bfloat16(v0.z), __float2bfloat16(v0.w),
                     __float2bfloat16(v1.x), __float2bfloat16(v1.y),
                     __float2bfloat16(v1.z), __float2bfloat16(v1.w)};
        *(short8_t*)&As[h * 2048 + tid * 8] = *(const short8_t*)t;
      }
    } else if (TST) {
      const bf16* Ag = (const bf16*)p.A + offA;
#pragma unroll
      for (int it = 0; it < 2; ++it) {
        int idx = it * 256 + tid;
        int tr = idx >> 4;   // k-local 0..31
        int ec = idx & 15;   // m-chunk 0..15 (8 rows each)
        short8_t v = *(const short8_t*)(Ag + (long)(kt + tr) * p.lda + tile_m + ec * 8);
#pragma unroll
        for (int j = 0; j < 8; ++j) As[(ec * 8 + j) * 32 + tr] = v[j];
      }
    } else {
      const bf16* Ag = (const bf16*)p.A + offA;
#pragma unroll
      for (int h = 0; h < 2; ++h)
        gload_lds16(Ag + (tile_m + h * 64 + row_s) * p.lda + kt + kc_s,
                    &As[h * 2048 + tid * 8]);
    }
    // ---- stage B tile [128][32] ----
    if (TST) {
      const bf16* Bg = (const bf16*)p.B + offB;
#pragma unroll
      for (int it = 0; it < 2; ++it) {
        int idx = it * 256 + tid;
        int tr = idx >> 4;
        int ec = idx & 15;
        short8_t v = *(const short8_t*)(Bg + (long)(kt + tr) * p.ldb + tile_n + ec * 8);
#pragma unroll
        for (int j = 0; j < 8; ++j) Bs[(ec * 8 + j) * 32 + tr] = v[j];
      }
    } else {
      const bf16* Bg = (const bf16*)p.B + offB;
#pragma unroll
      for (int h = 0; h < 2; ++h)
        gload_lds16(Bg + (tile_n + h * 64 + row_s) * p.ldb + kt + kc_s,
                    &Bs[h * 2048 + tid * 8]);
    }
    __syncthreads();

    // ---- fragments + 16 MFMA ----
    short8_t af[4], bfr[4];
#pragma unroll
    for (int m = 0; m < 4; ++m)
      af[m] = *(const short8_t*)&As[(wr * 64 + m * 16 + l16) * 32 + kg * 8];
#pragma unroll
    for (int n = 0; n < 4; ++n)
      bfr[n] = *(const short8_t*)&Bs[(wc * 64 + n * 16 + l16) * 32 + kg * 8];
#pragma unroll
    for (int m = 0; m < 4; ++m)
#pragma unroll
      for (int n = 0; n < 4; ++n)
        acc[m][n] = __builtin_amdgcn_mfma_f32_16x16x32_bf16(af[m], bfr[n], acc[m][n], 0, 0, 0);
    __syncthreads();
  }

  // ---- epilogue: C/D layout col=lane&15, row=(lane>>4)*4+reg (verified m89/m91) ----
#pragma unroll
  for (int n = 0; n < 4; ++n) {
    const long gcol = tile_n + wc * 64 + n * 16 + l16;
    const float bv = p.bias ? p.bias[gcol] : 0.f;
#pragma unroll
    for (int m = 0; m < 4; ++m) {
      const long grow = tile_m + wr * 64 + m * 16 + kg * 4;
#pragma unroll
      for (int r = 0; r < 4; ++r) {
        float val = p.alpha * (acc[m][n][r] + bv);
        long ci = offC + (grow + r) * p.ldc + gcol;
        if (OUT_MODE == 0)      ((bf16*)p.C)[ci] = __float2bfloat16(val);
        else if (OUT_MODE == 1) ((float*)p.C)[ci] = val;
        else                    atomicAdd((float*)p.C + ci, val);
      }
    }
  }
}

// ---------------------------------------------------------------------------
extern "C" void kernel_launch(void* const* d_in, const int* in_sizes, int n_in,
                              void* d_out, int out_size, void* d_ws, size_t ws_size,
                              hipStream_t stream) {
  const long Bb = 4, T = 4096, E = 2048, H = 16, D = 128;
  const long M = Bb * T;  // 16384

  const float* x  = (const float*)d_in[0];
  const float* bq = (const float*)d_in[2];
  const float* bk = (const float*)d_in[4];
  const float* bv = (const float*)d_in[6];
  const float* bo = (const float*)d_in[8];

  // workspace layout (bytes, all offsets 256-aligned)
  // small: W16(33.5M) + Q/K/V(201M) + KV(4.2M) + KVT(2.1M)            = 241,172,480
  // big:   + x16(67.1M)                                               = 308,281,344
  const size_t NEED_BIG = 308281344ull;
  const bool use_x16 = ws_size >= NEED_BIG;

  char* ws = (char*)d_ws;
  bf16* W16q = (bf16*)ws;
  bf16* W16k = W16q + E * E;
  bf16* W16v = W16k + E * E;
  bf16* W16o = W16v + E * E;
  char* cur = ws + 4 * E * E * 2;  // 33,554,432
  bf16* x16 = nullptr;
  if (use_x16) { x16 = (bf16*)cur; cur += M * E * 2; }
  bf16* Q16 = (bf16*)cur; cur += M * E * 2;
  bf16* K16 = (bf16*)cur; cur += M * E * 2;
  bf16* V16 = (bf16*)cur; cur += M * E * 2;
  float* KV = (float*)cur; cur += Bb * H * D * D * 4;
  bf16* KVT = (bf16*)cur;
  bf16* attn = K16;  // K is dead after the KV GEMM; reuse its buffer

  // 1) weights fp32 -> bf16 (and x, if ws allows)
  int wn8 = (int)(E * E / 8);
  int wgrid = (wn8 + 255) / 256;
  cvt_f32_bf16_k<<<wgrid, 256, 0, stream>>>((const float*)d_in[1], W16q, wn8);
  cvt_f32_bf16_k<<<wgrid, 256, 0, stream>>>((const float*)d_in[3], W16k, wn8);
  cvt_f32_bf16_k<<<wgrid, 256, 0, stream>>>((const float*)d_in[5], W16v, wn8);
  cvt_f32_bf16_k<<<wgrid, 256, 0, stream>>>((const float*)d_in[7], W16o, wn8);
  if (use_x16) {
    int xn8 = (int)(M * E / 8);
    cvt_f32_bf16_k<<<(xn8 + 255) / 256, 256, 0, stream>>>(x, x16, xn8);
  }

  // 2) projections: Q/K/V = x @ W^T + b
  dim3 g1(M / 128, E / 128, 1);
  GemmP p{};
  p.lda = E; p.ldb = E; p.ldc = E;
  p.sA1 = p.sA2 = p.sB1 = p.sB2 = p.sC1 = p.sC2 = 0;
  p.M = (int)M; p.N = (int)E; p.K = (int)E; p.HH = 1; p.splitk = 1; p.alpha = 1.f;
  if (use_x16) {
    p.A = x16;
    p.B = W16q; p.bias = bq; p.C = Q16; gemm_k<0, 0, 0><<<g1, 256, 0, stream>>>(p);
    p.B = W16k; p.bias = bk; p.C = K16; gemm_k<0, 0, 0><<<g1, 256, 0, stream>>>(p);
    p.B = W16v; p.bias = bv; p.C = V16; gemm_k<0, 0, 0><<<g1, 256, 0, stream>>>(p);
  } else {
    p.A = x;
    p.B = W16q; p.bias = bq; p.C = Q16; gemm_k<0, 1, 0><<<g1, 256, 0, stream>>>(p);
    p.B = W16k; p.bias = bk; p.C = K16; gemm_k<0, 1, 0><<<g1, 256, 0, stream>>>(p);
    p.B = W16v; p.bias = bv; p.C = V16; gemm_k<0, 1, 0><<<g1, 256, 0, stream>>>(p);
  }

  // 3) KV^T[e][d] = sum_t V[t][e] * K[t][d], per (b,h); split-K=4 via f32 atomics
  hipMemsetAsync(KV, 0, Bb * H * D * D * sizeof(float), stream);
  GemmP p2{};
  p2.A = V16; p2.B = K16; p2.bias = nullptr; p2.C = KV;
  p2.lda = E; p2.ldb = E; p2.ldc = D;
  p2.sA1 = T * E; p2.sA2 = D;      // batch = b*16+h -> b*T*E + h*128
  p2.sB1 = T * E; p2.sB2 = D;
  p2.sC1 = H * D * D; p2.sC2 = D * D;
  p2.M = (int)D; p2.N = (int)D; p2.K = (int)T; p2.HH = (int)H; p2.splitk = 4; p2.alpha = 1.f;
  gemm_k<2, 0, 1><<<dim3(1, 1, Bb * H * 4), 256, 0, stream>>>(p2);

  // 4) KV f32 -> bf16
  int kvn8 = (int)(Bb * H * D * D / 8);
  cvt_f32_bf16_k<<<(kvn8 + 255) / 256, 256, 0, stream>>>(KV, KVT, kvn8);

  // 5) attn = scale * (Q @ KVT^T), per (b,h); written into [b,t,h*128+e] layout
  GemmP p3{};
  p3.A = Q16; p3.B = KVT; p3.bias = nullptr; p3.C = attn;
  p3.lda = E; p3.ldb = D; p3.ldc = E;
  p3.sA1 = T * E; p3.sA2 = D;
  p3.sB1 = H * D * D; p3.sB2 = D * D;
  p3.sC1 = T * E; p3.sC2 = D;
  p3.M = (int)T; p3.N = (int)D; p3.K = (int)D; p3.HH = (int)H; p3.splitk = 1;
  p3.alpha = 0.08838834764831843f;  // 1/sqrt(128)
  gemm_k<0, 0, 0><<<dim3(T / 128, 1, Bb * H), 256, 0, stream>>>(p3);

  // 6) out = attn @ Wo^T + bo  (fp32 out)
  GemmP p4{};
  p4.A = attn; p4.B = W16o; p4.bias = bo; p4.C = d_out;
  p4.lda = E; p4.ldb = E; p4.ldc = E;
  p4.sA1 = p4.sA2 = p4.sB1 = p4.sB2 = p4.sC1 = p4.sC2 = 0;
  p4.M = (int)M; p4.N = (int)E; p4.K = (int)E; p4.HH = 1; p4.splitk = 1; p4.alpha = 1.f;
  gemm_k<1, 0, 0><<<g1, 256, 0, stream>>>(p4);
}